// Round 16
// baseline (275.148 us; speedup 1.0000x reference)
//
#include <hip/hip_runtime.h>
#include <hip/hip_bf16.h>

#define D_MODEL 1024
#define N_HEADS 16
#define DK 64
#define B_SZ 4
#define T_SEQ 2048
#define M_ROWS (B_SZ * T_SEQ)   // 8192
#define QK_SCALE_LOG2 0.18033688f   // 0.125 * log2(e), folded into W_qkv Q-rows

#define XN ((size_t)M_ROWS * D_MODEL)        // 8388608
#define WQ ((size_t)3 * D_MODEL * D_MODEL)   // 3145728
#define WP ((size_t)D_MODEL * D_MODEL)       // 1048576

typedef short bf16x8 __attribute__((ext_vector_type(8)));
typedef float f32x4  __attribute__((ext_vector_type(4)));

__device__ inline unsigned short f32_to_bf16(float f) {
    union { float f; unsigned int u; } v; v.f = f;
    unsigned int r = v.u + 0x7fff + ((v.u >> 16) & 1);   // RNE
    return (unsigned short)(r >> 16);
}
__device__ inline unsigned int pack_bf16x2(float a, float b) {
    __hip_bfloat162 t = __float22bfloat162_rn(make_float2(a, b));
    union { __hip_bfloat162 v; unsigned int u; } c; c.v = t;
    return c.u;   // low 16 = a
}

// ---------------------------------------------------------------------------
// Single cast kernel for all three fp32->bf16 planes (linear layouts).
// W_qkv's first D*D elements (Q rows) get the QK scale folded in.
// ---------------------------------------------------------------------------
__global__ __launch_bounds__(256) void cast_all(
    const float* __restrict__ x, const float* __restrict__ W_qkv,
    const float* __restrict__ W_proj,
    unsigned short* __restrict__ xb, unsigned short* __restrict__ wqb,
    unsigned short* __restrict__ wpb)
{
    const size_t total = (XN + WQ + WP) / 4;
    for (size_t i4 = blockIdx.x * 256 + threadIdx.x; i4 < total;
         i4 += gridDim.x * 256) {
        const size_t i = i4 * 4;
        const float* src; unsigned short* dst; float sc = 1.0f; size_t off;
        if (i < XN) {
            src = x; dst = xb; off = i;
        } else if (i < XN + WQ) {
            off = i - XN; src = W_qkv; dst = wqb;
            if (off < (size_t)D_MODEL * D_MODEL) sc = QK_SCALE_LOG2;
        } else {
            off = i - XN - WQ; src = W_proj; dst = wpb;
        }
        float4 v = *(const float4*)(src + off);
        ushort4 h;
        h.x = f32_to_bf16(v.x * sc); h.y = f32_to_bf16(v.y * sc);
        h.z = f32_to_bf16(v.z * sc); h.w = f32_to_bf16(v.w * sc);
        *(ushort4*)(dst + off) = h;
    }
}

// ---------------------------------------------------------------------------
// R25: 256x256 8-phase GEMM (T2+T3+T4+T5 port of the m201 template).
// 512 threads = 8 waves (2M x 4N); per-wave output 128x64 (acc[8][4]).
// BK=64; LDS = 2 dbuf x 2 half x [128][64] x {A,B} = 128 KB; 1 block/CU.
// Per iteration: 2 K-tiles, 8 phases. Each phase: stage ONE half-tile of a
// future K-tile (2 x global_load_lds), raw s_barrier, ds_read one quadrant
// (+ B frags at window open), 16 MFMA under setprio. Counted vmcnt(2) only
// at window-open phases (stage issued first -> own 2 stay in flight; the 8
// older = the buffer about to be read). Never vmcnt(0) except final window.
// Race-safety: stages into buf X occur only during the window computing
// buf X^1; window-end barrier separates last reads from next writes.
// Swizzle identical to attn/R22 (chunk ^= row&7, pre-swizzled source),
// measured 0 bank conflicts for 9 rounds at this geometry.
// FUSE_VT: V tiles (n0 >= 2*D_MODEL) write attn-ready vt fragments.
// ---------------------------------------------------------------------------
#define STAGE(SDBUF, PLANE, H, KT) do {                                       \
    const unsigned short* _g = (PLANE) ? B : A;                               \
    const int _r0 = ((PLANE) ? n0 : m0) + (H) * 128;                          \
    unsigned short* _l = ((PLANE) ? lds_b : lds_a) + ((SDBUF)*2 + (H)) * 8192;\
    _Pragma("unroll")                                                         \
    for (int _j = 0; _j < 2; ++_j) {                                          \
        __builtin_amdgcn_global_load_lds(                                     \
            (const __attribute__((address_space(1))) unsigned int*)           \
                (_g + (size_t)(_r0 + _j * 64 + srow) * K + (KT) * 64 + scg*8),\
            (__attribute__((address_space(3))) unsigned int*)                 \
                (_l + (_j * 64 + wid * 8) * 64),                              \
            16, 0, 0);                                                        \
    } } while (0)

#define GWIN(SAH, SBH, SDBUF, SKT, DOSTAGE, GATE2)                            \
  {                                                                           \
    _Pragma("unroll")                                                         \
    for (int q = 0; q < 4; ++q) {                                             \
      if (DOSTAGE) {                                                          \
        if      (q == 0) STAGE(SDBUF, 1, 0, SKT);                             \
        else if (q == 1) STAGE(SDBUF, 1, 1, SKT);                             \
        else if (q == 2) STAGE(SDBUF, 0, 0, SKT);                             \
        else             STAGE(SDBUF, 0, 1, SKT);                             \
      }                                                                       \
      if (q == 0) {                                                           \
        __builtin_amdgcn_sched_barrier(0);                                    \
        if (GATE2) asm volatile("s_waitcnt vmcnt(2)" ::: "memory");           \
        else       asm volatile("s_waitcnt vmcnt(0)" ::: "memory");           \
        __builtin_amdgcn_s_barrier();                                         \
        __builtin_amdgcn_sched_barrier(0);                                    \
        _Pragma("unroll")                                                     \
        for (int nf = 0; nf < 4; ++nf)                                        \
          _Pragma("unroll")                                                   \
          for (int kk = 0; kk < 2; ++kk)                                      \
            bfr[nf][kk] = *(const bf16x8*)&(SBH)[                             \
                (rb0 + nf * 16 + l15) * 64 + (((kk * 4 + quad) ^ swz) * 8)];  \
      } else {                                                                \
        __builtin_amdgcn_s_barrier();                                         \
      }                                                                       \
      bf16x8 afr[2][2];                                                       \
      _Pragma("unroll")                                                       \
      for (int sub = 0; sub < 2; ++sub)                                       \
        _Pragma("unroll")                                                     \
        for (int kk = 0; kk < 2; ++kk)                                        \
          afr[sub][kk] = *(const bf16x8*)&(SAH)[                              \
              ((q * 2 + sub) * 16 + l15) * 64 + (((kk*4 + quad) ^ swz) * 8)]; \
      __builtin_amdgcn_s_setprio(1);                                          \
      _Pragma("unroll")                                                       \
      for (int kk = 0; kk < 2; ++kk)                                          \
        _Pragma("unroll")                                                     \
        for (int sub = 0; sub < 2; ++sub)                                     \
          _Pragma("unroll")                                                   \
          for (int nf = 0; nf < 4; ++nf)                                      \
            acc[q * 2 + sub][nf] = __builtin_amdgcn_mfma_f32_16x16x32_bf16(   \
                afr[sub][kk], bfr[nf][kk], acc[q * 2 + sub][nf], 0, 0, 0);    \
      __builtin_amdgcn_s_setprio(0);                                          \
    }                                                                         \
    __builtin_amdgcn_s_barrier();                                             \
  }

template <typename OutT, bool FUSE_VT>
__global__ __launch_bounds__(512, 2) void gemm256(
    const unsigned short* __restrict__ A, const unsigned short* __restrict__ B,
    OutT* __restrict__ C, unsigned short* __restrict__ vt,
    int M, int N, int K, int nbx)
{
    __shared__ __align__(16) unsigned short lds_a[2 * 2 * 8192];  // 64 KB
    __shared__ __align__(16) unsigned short lds_b[2 * 2 * 8192];  // 64 KB

    const int t    = threadIdx.x;
    const int wid  = t >> 6;
    const int lane = t & 63;
    const int l15  = lane & 15;
    const int quad = lane >> 4;
    const int swz  = l15 & 7;

    // T1 bijective XCD swizzle (gridDim.x % 8 == 0), N fastest.
    const int cpx = gridDim.x >> 3;
    const int wg  = (blockIdx.x & 7) * cpx + (blockIdx.x >> 3);
    const int n0  = (wg % nbx) * 256;
    const int m0  = (wg / nbx) * 256;

    const int wr = (wid >> 2) * 128;       // wave M offset: 0 / 128
    const int wc = (wid & 3) * 64;         // wave N offset: 0/64/128/192

    // staging addressing (per half-tile: 2 calls x 512 threads x 16B = 16KB)
    const int srow = t >> 3;               // 0..63 (row within 64-row strip)
    const int scg  = (t & 7) ^ (srow & 7); // pre-swizzled source chunk

    f32x4 acc[8][4];
#pragma unroll
    for (int i = 0; i < 8; ++i)
#pragma unroll
        for (int j = 0; j < 4; ++j) acc[i][j] = (f32x4){0.f, 0.f, 0.f, 0.f};

    // fragment read bases (this wave's A-half / B-half, per dbuf)
    const unsigned short* sAh0 = lds_a + (0 * 2 + (wr >> 7)) * 8192;
    const unsigned short* sAh1 = lds_a + (1 * 2 + (wr >> 7)) * 8192;
    const unsigned short* sBh0 = lds_b + (0 * 2 + (wc >> 7)) * 8192;
    const unsigned short* sBh1 = lds_b + (1 * 2 + (wc >> 7)) * 8192;
    const int rb0 = (wc & 64);             // row base within B-half

    bf16x8 bfr[4][2];

    // prologue: stage K-tile 0 -> buf0 (order B0,B1,A0,A1)
    STAGE(0, 1, 0, 0); STAGE(0, 1, 1, 0);
    STAGE(0, 0, 0, 0); STAGE(0, 0, 1, 0);

    const int nkt = K >> 6;                // 16 K-tiles
    const int nit = K >> 7;                // 8 iterations (2 K-tiles each)
    for (int it = 0; it < nit; ++it) {
        // window 0: compute buf0 (tile 2it), stage tile 2it+1 -> buf1
        GWIN(sAh0, sBh0, 1, 2 * it + 1, true, true);
        // window 1: compute buf1 (tile 2it+1), stage tile 2it+2 -> buf0
        const bool st = (2 * it + 2) < nkt;
        GWIN(sAh1, sBh1, 0, 2 * it + 2, st, st);
    }

    if constexpr (FUSE_VT) {
        if (n0 >= 2 * D_MODEL) {
            // V tile: write attn-ready vt fragments only (no qkvb write).
            const int mrow = m0 + wr;              // 128-aligned
            const int bb   = mrow >> 11;
            const int tile = (mrow & 2047) >> 7;
            const int hA   = (n0 + wc - 2 * D_MODEL) >> 6;
            unsigned short* vtile =
                vt + ((size_t)((bb * N_HEADS + hA) * (T_SEQ / 128) + tile))
                     * (16 * 64 * 8);
#pragma unroll
            for (int cc = 0; cc < 4; ++cc) {
                const int c = cc * 4 + quad;
#pragma unroll
                for (int nf = 0; nf < 4; ++nf) {
                    const int d = nf * 16 + l15;
                    uint4 p;
                    p.x = pack_bf16x2(acc[2*cc][nf][0],     acc[2*cc][nf][1]);
                    p.y = pack_bf16x2(acc[2*cc][nf][2],     acc[2*cc][nf][3]);
                    p.z = pack_bf16x2(acc[2*cc + 1][nf][0], acc[2*cc + 1][nf][1]);
                    p.w = pack_bf16x2(acc[2*cc + 1][nf][2], acc[2*cc + 1][nf][3]);
                    *(uint4*)(vtile + (c * 64 + d) * 8) = p;
                }
            }
            return;
        }
    }

#pragma unroll
    for (int mf = 0; mf < 8; ++mf)
#pragma unroll
        for (int r = 0; r < 4; ++r) {
            OutT* crow =
                C + (size_t)(m0 + wr + mf * 16 + quad * 4 + r) * N + n0 + wc + l15;
#pragma unroll
            for (int nf = 0; nf < 4; ++nf) {
                if constexpr (sizeof(OutT) == 2)
                    crow[nf * 16] = (OutT)f32_to_bf16(acc[mf][nf][r]);
                else
                    crow[nf * 16] = (OutT)acc[mf][nf][r];
            }
        }
}

// ---------------------------------------------------------------------------
// MFMA flash attention. R16 structure (best measured) — setprio around MFMA
// clusters, V at point of use from fragment-major global layout, K double-
// buffered via global_load_lds. Unchanged.
// ---------------------------------------------------------------------------
__global__ __launch_bounds__(256, 4) void attn_mfma(
    const unsigned short* __restrict__ qkvb,   // [B,T,3D] bf16 (Q pre-scaled)
    const unsigned short* __restrict__ vt,     // [bh][tile][16][64][8] bf16
    unsigned short* __restrict__ ob)           // [B,T,D] bf16
{
    __shared__ __align__(16) unsigned short Ksw[2][128 * 64];  // [kv][dk] swizzled

    const int t    = threadIdx.x;
    const int wave = t >> 6;
    const int lane = t & 63;
    const int l15  = t & 15;
    const int quad = lane >> 4;
    const int swz  = l15 & 7;

    const int b  = blockIdx.z;
    const int h  = blockIdx.y;
    const int q0 = blockIdx.x * 128;

    // Q fragments (loop-invariant): 2 q-subtiles x 2 dk-chunks
    bf16x8 qa[2][2];
#pragma unroll
    for (int qs = 0; qs < 2; ++qs) {
        const unsigned short* qrow =
            qkvb + ((size_t)(b * T_SEQ) + q0 + wave * 32 + qs * 16 + l15)
                   * (3 * D_MODEL) + h * DK;
        qa[qs][0] = *(const bf16x8*)(qrow + quad * 8);
        qa[qs][1] = *(const bf16x8*)(qrow + 32 + quad * 8);
    }

    f32x4 O[2][4], Lacc[2];
#pragma unroll
    for (int qs = 0; qs < 2; ++qs) {
        Lacc[qs] = (f32x4){0.f, 0.f, 0.f, 0.f};
#pragma unroll
        for (int nd = 0; nd < 4; ++nd) O[qs][nd] = (f32x4){0.f, 0.f, 0.f, 0.f};
    }

    const short one_bf = (short)0x3F80;
    const bf16x8 ones8 = {one_bf, one_bf, one_bf, one_bf,
                          one_bf, one_bf, one_bf, one_bf};

    const unsigned short* kbase =
        qkvb + (size_t)(b * T_SEQ) * (3 * D_MODEL) + D_MODEL + h * DK;
    const unsigned short* vbase =
        vt + (size_t)(b * N_HEADS + h) * DK * T_SEQ;   // 16 tiles * 8192

    // K source-side swizzle (tile-invariant pieces)
    const int krl  = wave * 32 + (lane >> 3);
    const int kcol = ((lane & 7) ^ (lane >> 3)) * 8;

    // prologue: issue tile 0 K loads into buffer 0
#pragma unroll
    for (int i = 0; i < 4; ++i) {
        const int rk = krl + i * 8;
        __builtin_amdgcn_global_load_lds(
            (const __attribute__((address_space(1))) unsigned int*)
                (kbase + (size_t)rk * (3 * D_MODEL) + kcol),
            (__attribute__((address_space(3))) unsigned int*)
                (&Ksw[0][(wave * 4 + i) * 512]),
            16, 0, 0);
    }

    const int NT = T_SEQ / 128;
    for (int tile = 0; tile < NT; ++tile) {
        __syncthreads();   // drains this tile's K loads (issued one iter ago)

        if (tile + 1 < NT) {
            const int c0n = (tile + 1) * 128;
            const int nb  = (tile + 1) & 1;
#pragma unroll
            for (int i = 0; i < 4; ++i) {
                const int rk = krl + i * 8;
                __builtin_amdgcn_global_load_lds(
                    (const __attribute__((address_space(1))) unsigned int*)
                        (kbase + (size_t)(c0n + rk) * (3 * D_MODEL) + kcol),
                    (__attribute__((address_space(3))) unsigned int*)
                        (&Ksw[nb][(wave * 4 + i) * 512]),
                    16, 0, 0);
            }
        }

        const int cb = tile & 1;
        const unsigned short* vtile = vbase + (size_t)tile * (16 * 64 * 8);
        const unsigned short* vlane = vtile + quad * 512 + l15 * 8;
#pragma unroll
        for (int half = 0; half < 2; ++half) {
            f32x4 S[2][4];
#pragma unroll
            for (int qs = 0; qs < 2; ++qs)
#pragma unroll
                for (int nf = 0; nf < 4; ++nf) S[qs][nf] = (f32x4){0.f, 0.f, 0.f, 0.f};

            __builtin_amdgcn_s_setprio(1);
#pragma unroll
            for (int ks = 0; ks < 2; ++ks) {
                const int ch = ks * 4 + quad;
#pragma unroll
                for (int nf = 0; nf < 4; ++nf) {
                    const int row = half * 64 + nf * 16 + l15;   // kv
                    const bf16x8 kf =
                        *(const bf16x8*)&Ksw[cb][row * 64 + ((ch ^ swz) * 8)];
                    S[0][nf] = __builtin_amdgcn_mfma_f32_16x16x32_bf16(
                        kf, qa[0][ks], S[0][nf], 0, 0, 0);
                    S[1][nf] = __builtin_amdgcn_mfma_f32_16x16x32_bf16(
                        kf, qa[1][ks], S[1][nf], 0, 0, 0);
                }
            }
            __builtin_amdgcn_s_setprio(0);

#pragma unroll
            for (int gl = 0; gl < 2; ++gl) {
                bf16x8 pf[2];
#pragma unroll
                for (int qs = 0; qs < 2; ++qs) {
                    union { uint4 u; bf16x8 v; } cv;
                    const f32x4 s0 = S[qs][2 * gl];
                    const f32x4 s1 = S[qs][2 * gl + 1];
                    cv.u.x = pack_bf16x2(__builtin_amdgcn_exp2f(s0[0]),
                                         __builtin_amdgcn_exp2f(s0[1]));
                    cv.u.y = pack_bf16x2(__builtin_amdgcn_exp2f(s0[2]),
                                         __builtin_amdgcn_exp2f(s0[3]));
                    cv.u.z = pack_bf16x2(__builtin_amdgcn_exp2f(s1[0]),
                                         __builtin_amdgcn_exp2f(s1[1]));
                    cv.u.w = pack_bf16x2(__builtin_amdgcn_exp2f(s1[2]),
                                         __builtin_amdgcn_exp2f(s1[3]));
                    pf[qs] = cv.v;
                }
                const int g = half * 2 + gl;
                const unsigned short* vptr = vlane + (size_t)g * 2048;
                __builtin_amdgcn_s_setprio(1);
#pragma unroll
                for (int nd = 0; nd < 4; ++nd) {
                    const bf16x8 vb = *(const bf16x8*)(vptr + nd * 128);
                    O[0][nd] = __builtin_amdgcn_mfma_f32_16x16x32_bf16(
                        pf[0], vb, O[0][nd], 0, 0, 0);
                    O[1][nd] = __builtin_amdgcn_mfma_f32_16x16x32_bf16(
                        pf[1], vb, O[1][nd], 0, 0, 0);
                }
                Lacc[0] = __builtin_amdgcn_mfma_f32_16x16x32_bf16(
                    pf[0], ones8, Lacc[0], 0, 0, 0);
                Lacc[1] = __builtin_amdgcn_mfma_f32_16x16x32_bf16(
                    pf[1], ones8, Lacc[1], 0, 0, 0);
                __builtin_amdgcn_s_setprio(0);
            }
        }
    }

    // epilogue: single bf16 plane
#pragma unroll
    for (int qs = 0; qs < 2; ++qs)
#pragma unroll
        for (int r = 0; r < 4; ++r) {
            const float invl = 1.0f / Lacc[qs][r];
            const size_t rowbase =
                ((size_t)(b * T_SEQ) + q0 + wave * 32 + qs * 16 + quad * 4 + r)
                * D_MODEL + h * DK + l15;
#pragma unroll
            for (int nd = 0; nd < 4; ++nd)
                ob[rowbase + nd * 16] = f32_to_bf16(O[qs][nd][r] * invl);
        }
}

// ---------------------------------------------------------------------------
extern "C" void kernel_launch(void* const* d_in, const int* in_sizes, int n_in,
                              void* d_out, int out_size, void* d_ws, size_t ws_size,
                              hipStream_t stream)
{
    const float* x      = (const float*)d_in[0];
    const float* W_qkv  = (const float*)d_in[1];
    const float* W_proj = (const float*)d_in[2];
    float* out = (float*)d_out;

    unsigned short* xb   = (unsigned short*)d_ws;
    unsigned short* wqb  = xb + XN;
    unsigned short* wpb  = wqb + WQ;
    unsigned short* qkvb = wpb + WP;
    unsigned short* vtb  = qkvb + (size_t)M_ROWS * 3 * D_MODEL;
    unsigned short* ab   = xb;   // overlay (x plane dead after QKV GEMM)

    cast_all<<<1024, dim3(256), 0, stream>>>(x, W_qkv, W_proj, xb, wqb, wpb);

    // QKV GEMM (+fused vt build): 12 N-tiles x 32 M-tiles = 384 blocks (%8==0)
    gemm256<unsigned short, true>
        <<<dim3((3 * D_MODEL / 256) * (M_ROWS / 256)), dim3(512), 0, stream>>>(
        xb, wqb, qkvb, vtb, M_ROWS, 3 * D_MODEL, D_MODEL, 3 * D_MODEL / 256);

    attn_mfma<<<dim3(T_SEQ / 128, N_HEADS, B_SZ), dim3(256), 0, stream>>>(
        qkvb, vtb, ab);

    // proj GEMM: 4 N-tiles x 32 M-tiles = 128 blocks (%8==0)
    gemm256<float, false>
        <<<dim3((D_MODEL / 256) * (M_ROWS / 256)), dim3(512), 0, stream>>>(
        ab, wpb, out, nullptr, M_ROWS, D_MODEL, D_MODEL, D_MODEL / 256);
}